// Round 1
// 1693.669 us; speedup vs baseline: 1.1377x; 1.1377x over previous
//
#include <hip/hip_runtime.h>
#include <hip/hip_bf16.h>

// Problem constants (HunYuan MoE V1): T=B*S=2048 tokens, HID=2048, FF=4096,
// 8 experts top-2 + shared MLP. All inputs fp32; output fp32 [2,1024,2048].
#define T_TOK 2048
#define HID   2048
#define FF    4096
#define NE    8

typedef __bf16 bf16_t;
typedef bf16_t bf16x8 __attribute__((ext_vector_type(8)));
typedef float  f32x4  __attribute__((ext_vector_type(4)));

static constexpr int BM = 128;
static constexpr int BN = 128;

// gateup tiling: BK=32 keeps staging regs small next to the 128-reg dual acc
static constexpr int GK  = 32;
static constexpr int LDB = GK + 8;    // padded bf16 row for reg-staged B tiles

// down tiling: single acc -> afford BK=64 (half the barriers)
static constexpr int DK  = 64;
static constexpr int LDD = DK + 8;

// async global->LDS, 16B per lane; LDS dest is wave-uniform base + lane*16
__device__ __forceinline__ void gload_lds16(const void* g, void* l) {
    __builtin_amdgcn_global_load_lds(
        (const __attribute__((address_space(1))) void*)g,
        (__attribute__((address_space(3))) void*)l, 16, 0, 0);
}

// ---------------------------------------------------------------------------
// Router: one wave per token. fp32 logits -> softmax -> top2 -> renormalize.
// Also emits x as bf16 (xb) so the GEMMs can stage A via global_load_lds.
// ---------------------------------------------------------------------------
__global__ __launch_bounds__(256) void router_kernel(
    const float* __restrict__ x, const float* __restrict__ wg,
    int* __restrict__ counts, int* __restrict__ plist, float* __restrict__ wlist,
    bf16_t* __restrict__ xb)
{
    const int wave = threadIdx.x >> 6;
    const int lane = threadIdx.x & 63;
    const int t = blockIdx.x * 4 + wave;

    const float* xp = x + (size_t)t * HID;
    float xr[32];
#pragma unroll
    for (int i = 0; i < 32; i++) xr[i] = xp[lane + 64 * i];

    // emit bf16 copy of x
    bf16_t* xbp = xb + (size_t)t * HID;
#pragma unroll
    for (int i = 0; i < 32; i++) xbp[lane + 64 * i] = (bf16_t)xr[i];

    float lg[NE];
#pragma unroll
    for (int e = 0; e < NE; e++) {
        const float* w = wg + e * HID;
        float s = 0.f;
#pragma unroll
        for (int i = 0; i < 32; i++) s += xr[i] * w[lane + 64 * i];
#pragma unroll
        for (int off = 32; off > 0; off >>= 1) s += __shfl_xor(s, off, 64);
        lg[e] = s;
    }

    float mx = lg[0];
#pragma unroll
    for (int e = 1; e < NE; e++) mx = fmaxf(mx, lg[e]);
    float p[NE];
#pragma unroll
    for (int e = 0; e < NE; e++) p[e] = __expf(lg[e] - mx);

    int i1 = 0; float p1 = p[0];
#pragma unroll
    for (int e = 1; e < NE; e++) if (p[e] > p1) { p1 = p[e]; i1 = e; }
    int i2 = -1; float p2 = -1.f;
#pragma unroll
    for (int e = 0; e < NE; e++) if (e != i1 && p[e] > p2) { p2 = p[e]; i2 = e; }
    const float inv = 1.f / (p1 + p2);

    if (lane == 0) {
        int pos = atomicAdd(&counts[i1], 1);
        plist[i1 * T_TOK + pos] = t * 2;
        wlist[i1 * T_TOK + pos] = p1 * inv;
        pos = atomicAdd(&counts[i2], 1);
        plist[i2 * T_TOK + pos] = t * 2 + 1;
        wlist[i2 * T_TOK + pos] = p2 * inv;
    }
}

// ---------------------------------------------------------------------------
// Fused gate+up GEMM, single-barrier double-buffered pipeline.
// A = xb bf16 (gathered rows) staged via global_load_lds (XOR-swizzled source,
// linear LDS, XOR on ds_read). B gate/up = fp32 weights reg-staged (T14 split:
// loads issued before MFMA phase, cvt+write after, to the other buffer).
// Epilogue: H[p, f] = bf16(silu(g)*u).
// ---------------------------------------------------------------------------
__global__ __launch_bounds__(256, 2) void gateup_kernel(
    const bf16_t* __restrict__ xb,
    const float* __restrict__ ex_gate, const float* __restrict__ ex_up,
    const float* __restrict__ sh_gate, const float* __restrict__ sh_up,
    const int* __restrict__ counts, const int* __restrict__ plist,
    bf16_t* __restrict__ H)
{
    const int z = blockIdx.z;
    const int count = (z == NE) ? T_TOK : counts[z];
    const int m0 = blockIdx.y * BM;
    if (m0 >= count) return;
    const int n0 = blockIdx.x * BN;

    const float* Bg = (z == NE) ? sh_gate : ex_gate + (size_t)z * FF * HID;
    const float* Bu = (z == NE) ? sh_up   : ex_up   + (size_t)z * FF * HID;

    __shared__ __align__(16) bf16_t As [2][BM * GK];
    __shared__ __align__(16) bf16_t Bgs[2][BM * LDB];
    __shared__ __align__(16) bf16_t Bus[2][BM * LDB];
    __shared__ int prow[BM];
    __shared__ int arow[BM];

    const int tid = threadIdx.x;
    for (int r = tid; r < BM; r += 256) {
        int m = m0 + r;
        int pr, ar;
        if (z == NE) { pr = 4096 + m; ar = m; }
        else {
            int mm = (m < count) ? m : (count - 1);
            pr = plist[z * T_TOK + mm];
            ar = pr >> 1;
        }
        prow[r] = pr; arow[r] = ar;
    }
    __syncthreads();

    const int wave = tid >> 6, lane = tid & 63;
    const int wr = (wave >> 1) * 64, wc = (wave & 1) * 64;
    const int lr = lane & 15;
    const int q  = lane >> 4;

    // --- A DMA setup: 2 issues/wave, each 16 rows x 64B. lane -> (row=lane>>2,
    // chunk=lane&3); source chunk XOR-swizzled by (row&3) so LDS stays linear.
    const int arl0 = wave * 32 + (lane >> 2);
    const int arl1 = arl0 + 16;
    const int axoff = ((lane & 3) ^ ((lane >> 2) & 3)) * 8;   // elements
    const bf16_t* aptr0 = xb + (size_t)arow[arl0] * HID + axoff;
    const bf16_t* aptr1 = xb + (size_t)arow[arl1] * HID + axoff;
    const int awoff0 = (wave * 32) * GK;
    const int awoff1 = (wave * 32 + 16) * GK;

    // --- B reg-staging: thread -> (row = tid/2, 16-float half = tid&1)
    const int srow = tid >> 1;
    const int sh16 = (tid & 1) * 16;
    const float* gsrc = Bg + (size_t)(n0 + srow) * HID + sh16;
    const float* usrc = Bu + (size_t)(n0 + srow) * HID + sh16;
    const int boff = srow * LDB + sh16;

    f32x4 accg[4][4] = {};
    f32x4 accu[4][4] = {};
    f32x4 sg[4], su[4];

    // prologue: stage tile 0 into buffer 0
    gload_lds16(aptr0, &As[0][awoff0]);
    gload_lds16(aptr1, &As[0][awoff1]);
    {
        const f32x4* g4 = (const f32x4*)gsrc;
        const f32x4* u4 = (const f32x4*)usrc;
#pragma unroll
        for (int i = 0; i < 4; i++) { sg[i] = g4[i]; su[i] = u4[i]; }
        bf16_t* gd = &Bgs[0][boff];
        bf16_t* ud = &Bus[0][boff];
#pragma unroll
        for (int i = 0; i < 2; i++) {
            bf16x8 hg, hu;
#pragma unroll
            for (int e = 0; e < 4; e++) {
                hg[e] = (bf16_t)sg[2 * i][e]; hg[4 + e] = (bf16_t)sg[2 * i + 1][e];
                hu[e] = (bf16_t)su[2 * i][e]; hu[4 + e] = (bf16_t)su[2 * i + 1][e];
            }
            *(bf16x8*)(gd + 8 * i) = hg;
            *(bf16x8*)(ud + 8 * i) = hu;
        }
    }
    __syncthreads();   // vmcnt(0) drain -> As[0] complete, B[0] written

    const int NT = HID / GK;   // 64
    int cur = 0;
    for (int t = 0; t < NT; ++t) {
        const int nxt = cur ^ 1;
        const bool hn = (t + 1) < NT;
        const int k1 = (t + 1) * GK;

        if (hn) {
            // next tile in flight under this tile's MFMA phase
            gload_lds16(aptr0 + k1, &As[nxt][awoff0]);
            gload_lds16(aptr1 + k1, &As[nxt][awoff1]);
            const f32x4* g4 = (const f32x4*)(gsrc + k1);
            const f32x4* u4 = (const f32x4*)(usrc + k1);
#pragma unroll
            for (int i = 0; i < 4; i++) { sg[i] = g4[i]; su[i] = u4[i]; }
        }

        // MFMA phase on buffer `cur`
        bf16x8 af[4], bg[4], bu[4];
#pragma unroll
        for (int i = 0; i < 4; i++) {
            int r = wr + 16 * i + lr;
            af[i] = *(const bf16x8*)(&As[cur][r * GK + ((q ^ (r & 3)) * 8)]);
        }
#pragma unroll
        for (int j = 0; j < 4; j++) {
            int rb = wc + 16 * j + lr;
            bg[j] = *(const bf16x8*)(&Bgs[cur][rb * LDB + q * 8]);
            bu[j] = *(const bf16x8*)(&Bus[cur][rb * LDB + q * 8]);
        }
#pragma unroll
        for (int i = 0; i < 4; i++)
#pragma unroll
            for (int j = 0; j < 4; j++) {
                accg[i][j] = __builtin_amdgcn_mfma_f32_16x16x32_bf16(af[i], bg[j], accg[i][j], 0, 0, 0);
                accu[i][j] = __builtin_amdgcn_mfma_f32_16x16x32_bf16(af[i], bu[j], accu[i][j], 0, 0, 0);
            }

        if (hn) {
            // cvt+write next B into the buffer nobody reads this step
            bf16_t* gd = &Bgs[nxt][boff];
            bf16_t* ud = &Bus[nxt][boff];
#pragma unroll
            for (int i = 0; i < 2; i++) {
                bf16x8 hg, hu;
#pragma unroll
                for (int e = 0; e < 4; e++) {
                    hg[e] = (bf16_t)sg[2 * i][e]; hg[4 + e] = (bf16_t)sg[2 * i + 1][e];
                    hu[e] = (bf16_t)su[2 * i][e]; hu[4 + e] = (bf16_t)su[2 * i + 1][e];
                }
                *(bf16x8*)(gd + 8 * i) = hg;
                *(bf16x8*)(ud + 8 * i) = hu;
            }
        }
        __syncthreads();   // one barrier per K-step
        cur = nxt;
    }

    // epilogue: h = silu(g)*u -> bf16 H[p, col]
#pragma unroll
    for (int i = 0; i < 4; i++) {
#pragma unroll
        for (int r = 0; r < 4; r++) {
            int row = wr + 16 * i + q * 4 + r;
            if (m0 + row < count) {
                bf16_t* hb = H + (size_t)prow[row] * FF + n0 + wc + lr;
#pragma unroll
                for (int j = 0; j < 4; j++) {
                    float g = accg[i][j][r], u = accu[i][j][r];
                    float h = g * (1.f / (1.f + __expf(-g))) * u;
                    hb[16 * j] = (bf16_t)h;
                }
            }
        }
    }
}

// ---------------------------------------------------------------------------
// Down projection, same pipeline. A = H bf16 (global_load_lds, swizzled src),
// B = Wd fp32 reg-staged. BK=64. Epilogue: scaled atomicAdd into out (zeroed).
// ---------------------------------------------------------------------------
__global__ __launch_bounds__(256, 2) void down_kernel(
    const bf16_t* __restrict__ H,
    const float* __restrict__ ex_down, const float* __restrict__ sh_down,
    const int* __restrict__ counts, const int* __restrict__ plist,
    const float* __restrict__ wlist,
    float* __restrict__ out)
{
    const int z = blockIdx.z;
    const int count = (z == NE) ? T_TOK : counts[z];
    const int m0 = blockIdx.y * BM;
    if (m0 >= count) return;
    const int n0 = blockIdx.x * BN;

    const float* Bd = (z == NE) ? sh_down : ex_down + (size_t)z * HID * FF;

    __shared__ __align__(16) bf16_t As[2][BM * DK];
    __shared__ __align__(16) bf16_t Bs[2][BM * LDD];
    __shared__ int   hrow[BM];
    __shared__ int   trow[BM];
    __shared__ float wrow[BM];

    const int tid = threadIdx.x;
    for (int r = tid; r < BM; r += 256) {
        int m = m0 + r;
        if (z == NE) { hrow[r] = 4096 + m; trow[r] = m; wrow[r] = 1.f; }
        else {
            int mm = (m < count) ? m : (count - 1);
            int pp = plist[z * T_TOK + mm];
            hrow[r] = pp; trow[r] = pp >> 1; wrow[r] = wlist[z * T_TOK + mm];
        }
    }
    __syncthreads();

    const int wave = tid >> 6, lane = tid & 63;
    const int wr = (wave >> 1) * 64, wc = (wave & 1) * 64;
    const int lr = lane & 15;
    const int q  = lane >> 4;

    // A DMA: 4 issues/wave, each 8 rows x 128B. lane -> (row=lane>>3, chunk=lane&7),
    // source chunk XOR-swizzled by (row&7).
    const int axoff = ((lane & 7) ^ (lane >> 3)) * 8;    // elements
    const bf16_t* aptr[4];
    int awoff[4];
#pragma unroll
    for (int i = 0; i < 4; i++) {
        int rl = wave * 32 + i * 8 + (lane >> 3);
        aptr[i] = H + (size_t)hrow[rl] * FF + axoff;
        awoff[i] = (wave * 32 + i * 8) * DK;
    }

    // B reg-staging: thread -> (row = tid/2, 32-float half = tid&1)
    const int srow = tid >> 1;
    const int sh32 = (tid & 1) * 32;
    const float* bsrc = Bd + (size_t)(n0 + srow) * FF + sh32;
    const int boff = srow * LDD + sh32;

    f32x4 acc[4][4] = {};
    f32x4 sb[8];

    // prologue
#pragma unroll
    for (int i = 0; i < 4; i++) gload_lds16(aptr[i], &As[0][awoff[i]]);
    {
        const f32x4* b4 = (const f32x4*)bsrc;
#pragma unroll
        for (int i = 0; i < 8; i++) sb[i] = b4[i];
        bf16_t* bd = &Bs[0][boff];
#pragma unroll
        for (int i = 0; i < 4; i++) {
            bf16x8 hb;
#pragma unroll
            for (int e = 0; e < 4; e++) {
                hb[e] = (bf16_t)sb[2 * i][e]; hb[4 + e] = (bf16_t)sb[2 * i + 1][e];
            }
            *(bf16x8*)(bd + 8 * i) = hb;
        }
    }
    __syncthreads();

    const int NT = FF / DK;   // 64
    int cur = 0;
    for (int t = 0; t < NT; ++t) {
        const int nxt = cur ^ 1;
        const bool hn = (t + 1) < NT;
        const int k1 = (t + 1) * DK;

        if (hn) {
#pragma unroll
            for (int i = 0; i < 4; i++) gload_lds16(aptr[i] + k1, &As[nxt][awoff[i]]);
            const f32x4* b4 = (const f32x4*)(bsrc + k1);
#pragma unroll
            for (int i = 0; i < 8; i++) sb[i] = b4[i];
        }

#pragma unroll
        for (int kk = 0; kk < 2; kk++) {
            bf16x8 af[4], bf[4];
#pragma unroll
            for (int i = 0; i < 4; i++) {
                int r = wr + 16 * i + lr;
                af[i] = *(const bf16x8*)(&As[cur][r * DK + (((kk * 4 + q) ^ (r & 7)) * 8)]);
            }
#pragma unroll
            for (int j = 0; j < 4; j++) {
                int rb = wc + 16 * j + lr;
                bf[j] = *(const bf16x8*)(&Bs[cur][rb * LDD + kk * 32 + q * 8]);
            }
#pragma unroll
            for (int i = 0; i < 4; i++)
#pragma unroll
                for (int j = 0; j < 4; j++)
                    acc[i][j] = __builtin_amdgcn_mfma_f32_16x16x32_bf16(af[i], bf[j], acc[i][j], 0, 0, 0);
        }

        if (hn) {
            bf16_t* bd = &Bs[nxt][boff];
#pragma unroll
            for (int i = 0; i < 4; i++) {
                bf16x8 hb;
#pragma unroll
                for (int e = 0; e < 4; e++) {
                    hb[e] = (bf16_t)sb[2 * i][e]; hb[4 + e] = (bf16_t)sb[2 * i + 1][e];
                }
                *(bf16x8*)(bd + 8 * i) = hb;
            }
        }
        __syncthreads();
        cur = nxt;
    }

#pragma unroll
    for (int i = 0; i < 4; i++) {
#pragma unroll
        for (int r = 0; r < 4; r++) {
            int row = wr + 16 * i + q * 4 + r;
            if (m0 + row < count) {
                float w = wrow[row];
                float* ob = out + (size_t)trow[row] * HID + n0 + wc + lr;
#pragma unroll
                for (int j = 0; j < 4; j++)
                    atomicAdd(ob + 16 * j, w * acc[i][j][r]);
            }
        }
    }
}

// ---------------------------------------------------------------------------
// ws layout: [0,64) counts | [256,..) plist 8x2048 int | wlist 8x2048 float |
// H bf16 [6144, FF] | xb bf16 [T_TOK, HID]   (~59 MB total)
// ---------------------------------------------------------------------------
extern "C" void kernel_launch(void* const* d_in, const int* in_sizes, int n_in,
                              void* d_out, int out_size, void* d_ws, size_t ws_size,
                              hipStream_t stream)
{
    const float* x       = (const float*)d_in[0];
    const float* wg      = (const float*)d_in[1];
    const float* sh_gate = (const float*)d_in[2];
    const float* sh_up   = (const float*)d_in[3];
    const float* sh_down = (const float*)d_in[4];
    const float* ex_gate = (const float*)d_in[5];
    const float* ex_up   = (const float*)d_in[6];
    const float* ex_down = (const float*)d_in[7];
    float* out = (float*)d_out;

    char* ws = (char*)d_ws;
    int*    counts = (int*)ws;
    int*    plist  = (int*)(ws + 256);
    float*  wlist  = (float*)(ws + 256 + NE * T_TOK * 4);
    bf16_t* H      = (bf16_t*)(ws + 256 + 2 * NE * T_TOK * 4);
    bf16_t* xb     = (bf16_t*)(ws + 256 + 2 * NE * T_TOK * 4 + (size_t)6144 * FF * 2);

    hipMemsetAsync(counts, 0, 64, stream);
    hipMemsetAsync(d_out, 0, (size_t)out_size * sizeof(float), stream);

    router_kernel<<<T_TOK / 4, 256, 0, stream>>>(x, wg, counts, plist, wlist, xb);
    gateup_kernel<<<dim3(FF / BN, T_TOK / BM, NE + 1), 256, 0, stream>>>(
        xb, ex_gate, ex_up, sh_gate, sh_up, counts, plist, H);
    down_kernel<<<dim3(HID / BN, T_TOK / BM, NE + 1), 256, 0, stream>>>(
        H, ex_down, sh_down, counts, plist, wlist, out);
}